// Round 1
// baseline (1908.610 us; speedup 1.0000x reference)
//
#include <hip/hip_runtime.h>

// 2-layer stacked LSTM (shared cell), B=256, T=1024, F=UNITS=128.
// One workgroup per batch element (256 WGs, one per CU), full time loop
// in-kernel. Weights held in VGPRs as f16 pairs, MACs via v_dot2_f32_f16.
//
// d_out layout (f32): [0,32768) h2_final | [32768, 32768+33554432) zeros
//                     | [33587200, 33619968) c1_final

typedef _Float16 h16;
typedef _Float16 h16x2 __attribute__((ext_vector_type(2)));

#define T_STEPS 1024
#define UNITS   128

__device__ __forceinline__ float fdot2(h16x2 a, h16x2 b, float c) {
#if __has_builtin(__builtin_amdgcn_fdot2)
    return __builtin_amdgcn_fdot2(a, b, c, false);
#else
    float d;
    asm("v_dot2_f32_f16 %0, %1, %2, %3" : "=v"(d) : "v"(a), "v"(b), "v"(c));
    return d;
#endif
}

__device__ __forceinline__ float sigmoidf_(float x) {
    return 1.0f / (1.0f + __expf(-x));
}
// tanh via exp; saturates correctly at +/-1 for large |x|
__device__ __forceinline__ float tanhf_(float x) {
    float e = __expf(2.0f * x);
    return 1.0f - 2.0f / (e + 1.0f);
}

__global__ __launch_bounds__(512, 2) void lstm2_kernel(
    const float* __restrict__ X,   // [256][1024][128]
    const float* __restrict__ W,   // [128][512]  gate order i|f|g|o
    const float* __restrict__ U,   // [128][512]
    const float* __restrict__ Bv,  // [512]
    float* __restrict__ out)
{
    const int tid  = threadIdx.x;
    const int wave = tid >> 6;
    const int lane = tid & 63;
    const int cg   = lane & 15;      // column group within wave
    const int ks   = lane >> 4;      // k-slice (0..3), 32 k each
    const int j0   = wave * 64 + cg * 4;  // first of 4 owned gate columns
    const int k0   = ks * 32;
    const int b    = blockIdx.x;
    const size_t xbase = (size_t)b * (T_STEPS * UNITS);

    __shared__ __align__(16) h16 xbuf[UNITS];
    __shared__ __align__(16) h16 h1buf[UNITS];
    __shared__ __align__(16) h16 h2buf[UNITS];
    __shared__ __align__(16) float zp[4][512];   // per-kslice partial z

    // ---- load weights into registers: f16 pairs along K (pair k, k+1)
    h16x2 wW[16][4], wU[16][4];
    #pragma unroll
    for (int kk = 0; kk < 16; ++kk) {
        const float* wr0 = W + (size_t)(k0 + 2 * kk) * 512 + j0;
        const float* ur0 = U + (size_t)(k0 + 2 * kk) * 512 + j0;
        #pragma unroll
        for (int c = 0; c < 4; ++c) {
            h16x2 w, u;
            w[0] = (h16)wr0[c];       w[1] = (h16)wr0[512 + c];
            u[0] = (h16)ur0[c];       u[1] = (h16)ur0[512 + c];
            wW[kk][c] = w;            wU[kk][c] = u;
        }
    }
    float bias[4];
    #pragma unroll
    for (int c = 0; c < 4; ++c) bias[c] = (ks == 0) ? Bv[j0 + c] : 0.0f;

    float c1 = 0.0f, c2 = 0.0f;
    if (tid < UNITS) {
        h1buf[tid] = (h16)0.0f;
        h2buf[tid] = (h16)0.0f;
        xbuf[tid]  = (h16)X[xbase + tid];
    }
    __syncthreads();

    const uint4* xb4  = (const uint4*)xbuf;
    const uint4* h1b4 = (const uint4*)h1buf;
    const uint4* h2b4 = (const uint4*)h2buf;

    for (int t = 0; t < T_STEPS; ++t) {
        // prefetch next x (latency hidden under both cells' dot phases)
        // and emit this step's slice of the zeros output
        float xn = 0.0f;
        if (tid < UNITS) {
            if (t + 1 < T_STEPS) xn = X[xbase + (size_t)(t + 1) * UNITS + tid];
            out[(size_t)32768 + xbase + (size_t)t * UNITS + tid] = 0.0f;
        }

        // ================= cell 1: z = x@W + h1@U + b =================
        float acc0 = bias[0], acc1 = bias[1], acc2 = bias[2], acc3 = bias[3];
        #pragma unroll
        for (int q = 0; q < 4; ++q) {
            uint4 xv = xb4[ks * 4 + q];
            uint4 hv = h1b4[ks * 4 + q];
            const unsigned* xw = (const unsigned*)&xv;
            const unsigned* hw = (const unsigned*)&hv;
            #pragma unroll
            for (int p = 0; p < 4; ++p) {
                h16x2 xp = __builtin_bit_cast(h16x2, xw[p]);
                h16x2 hp = __builtin_bit_cast(h16x2, hw[p]);
                acc0 = fdot2(xp, wW[q * 4 + p][0], acc0);
                acc1 = fdot2(xp, wW[q * 4 + p][1], acc1);
                acc2 = fdot2(xp, wW[q * 4 + p][2], acc2);
                acc3 = fdot2(xp, wW[q * 4 + p][3], acc3);
                acc0 = fdot2(hp, wU[q * 4 + p][0], acc0);
                acc1 = fdot2(hp, wU[q * 4 + p][1], acc1);
                acc2 = fdot2(hp, wU[q * 4 + p][2], acc2);
                acc3 = fdot2(hp, wU[q * 4 + p][3], acc3);
            }
        }
        *(float4*)&zp[ks][j0] = make_float4(acc0, acc1, acc2, acc3);
        __syncthreads();

        if (tid < UNITS) {
            float zi = zp[0][tid]       + zp[1][tid]       + zp[2][tid]       + zp[3][tid];
            float zf = zp[0][tid + 128] + zp[1][tid + 128] + zp[2][tid + 128] + zp[3][tid + 128];
            float zg = zp[0][tid + 256] + zp[1][tid + 256] + zp[2][tid + 256] + zp[3][tid + 256];
            float zo = zp[0][tid + 384] + zp[1][tid + 384] + zp[2][tid + 384] + zp[3][tid + 384];
            float ig = sigmoidf_(zi), fg = sigmoidf_(zf);
            float gg = tanhf_(zg),    og = sigmoidf_(zo);
            c1 = fg * c1 + ig * gg;
            float h1v = og * tanhf_(c1);
            h1buf[tid] = (h16)h1v;
            if (t == T_STEPS - 1) out[(size_t)33587200 + b * UNITS + tid] = c1;
        }
        __syncthreads();

        // ================= cell 2: z = h1@W + h2@U + b =================
        acc0 = bias[0]; acc1 = bias[1]; acc2 = bias[2]; acc3 = bias[3];
        #pragma unroll
        for (int q = 0; q < 4; ++q) {
            uint4 xv = h1b4[ks * 4 + q];
            uint4 hv = h2b4[ks * 4 + q];
            const unsigned* xw = (const unsigned*)&xv;
            const unsigned* hw = (const unsigned*)&hv;
            #pragma unroll
            for (int p = 0; p < 4; ++p) {
                h16x2 xp = __builtin_bit_cast(h16x2, xw[p]);
                h16x2 hp = __builtin_bit_cast(h16x2, hw[p]);
                acc0 = fdot2(xp, wW[q * 4 + p][0], acc0);
                acc1 = fdot2(xp, wW[q * 4 + p][1], acc1);
                acc2 = fdot2(xp, wW[q * 4 + p][2], acc2);
                acc3 = fdot2(xp, wW[q * 4 + p][3], acc3);
                acc0 = fdot2(hp, wU[q * 4 + p][0], acc0);
                acc1 = fdot2(hp, wU[q * 4 + p][1], acc1);
                acc2 = fdot2(hp, wU[q * 4 + p][2], acc2);
                acc3 = fdot2(hp, wU[q * 4 + p][3], acc3);
            }
        }
        *(float4*)&zp[ks][j0] = make_float4(acc0, acc1, acc2, acc3);
        __syncthreads();

        if (tid < UNITS) {
            float zi = zp[0][tid]       + zp[1][tid]       + zp[2][tid]       + zp[3][tid];
            float zf = zp[0][tid + 128] + zp[1][tid + 128] + zp[2][tid + 128] + zp[3][tid + 128];
            float zg = zp[0][tid + 256] + zp[1][tid + 256] + zp[2][tid + 256] + zp[3][tid + 256];
            float zo = zp[0][tid + 384] + zp[1][tid + 384] + zp[2][tid + 384] + zp[3][tid + 384];
            float ig = sigmoidf_(zi), fg = sigmoidf_(zf);
            float gg = tanhf_(zg),    og = sigmoidf_(zo);
            c2 = fg * c2 + ig * gg;
            float h2v = og * tanhf_(c2);
            h2buf[tid] = (h16)h2v;
            if (t + 1 < T_STEPS) xbuf[tid] = (h16)xn;
            else                 out[b * UNITS + tid] = h2v;
        }
        __syncthreads();
    }
}

extern "C" void kernel_launch(void* const* d_in, const int* in_sizes, int n_in,
                              void* d_out, int out_size, void* d_ws, size_t ws_size,
                              hipStream_t stream) {
    const float* X  = (const float*)d_in[0];
    const float* W  = (const float*)d_in[1];
    const float* U  = (const float*)d_in[2];
    const float* Bv = (const float*)d_in[3];
    float* out = (float*)d_out;
    hipLaunchKernelGGL(lstm2_kernel, dim3(256), dim3(512), 0, stream,
                       X, W, U, Bv, out);
}